// Round 6
// baseline (174.293 us; speedup 1.0000x reference)
//
#include <hip/hip_runtime.h>
#include <cstdint>

using u16 = unsigned short;
typedef __bf16 bf16x8 __attribute__((ext_vector_type(8)));
typedef __bf16 bf16x4 __attribute__((ext_vector_type(4)));
typedef __bf16 bf16x2 __attribute__((ext_vector_type(2)));
typedef float f32x4 __attribute__((ext_vector_type(4)));

#define MFMA16(a, b, c) __builtin_amdgcn_mfma_f32_16x16x32_bf16((a), (b), (c), 0, 0, 0)

__device__ __forceinline__ u16 f2bf(float f) {
  union { float f; uint32_t u; } c; c.f = f;
  uint32_t u = c.u;
  u += 0x7fffu + ((u >> 16) & 1u);   // RNE
  return (u16)(u >> 16);
}

#if __has_builtin(__builtin_amdgcn_global_load_lds)
#define GLOAD_LDS16(g, l)                                                      \
  __builtin_amdgcn_global_load_lds(                                            \
      (__attribute__((address_space(1))) void*)(g),                            \
      (__attribute__((address_space(3))) void*)(l), 16, 0, 0)
#else
#define GLOAD_LDS16(g, l) do { *(uint4*)(l) = *(const uint4*)(g); } while (0)
#endif

// In-register P^T fragment build (replaces P LDS round-trip).
__device__ __forceinline__ bf16x8 ptrans(const f32x4 lo, const f32x4 hi) {
  union W { bf16x2 h; uint32_t u; } wl0, wl1, wh0, wh1;
  wl0.h[0] = (__bf16)lo[0]; wl0.h[1] = (__bf16)lo[1];
  wl1.h[0] = (__bf16)lo[2]; wl1.h[1] = (__bf16)lo[3];
  wh0.h[0] = (__bf16)hi[0]; wh0.h[1] = (__bf16)hi[1];
  wh1.h[0] = (__bf16)hi[2]; wh1.h[1] = (__bf16)hi[3];
  uint32_t a0 = wl0.u, b0 = wh0.u, a1 = wl1.u, b1 = wh1.u;
  asm("v_permlane32_swap_b32 %0, %1" : "+v"(a0), "+v"(b0));
  asm("v_permlane16_swap_b32 %0, %1" : "+v"(a0), "+v"(b0));
  asm("v_permlane32_swap_b32 %0, %1" : "+v"(a1), "+v"(b1));
  asm("v_permlane16_swap_b32 %0, %1" : "+v"(a1), "+v"(b1));
  union R { uint32_t u[4]; bf16x8 v; } r;
  r.u[0] = a0; r.u[1] = a1; r.u[2] = b0; r.u[3] = b1;
  return r.v;
}

// ---------------- fused prep: x->bf16, w_qkv^T->bf16, w_out^T->bf16 --------
__global__ __launch_bounds__(256) void prep(
    const float* __restrict__ x, const float* __restrict__ w_qkv,
    const float* __restrict__ w_out, u16* __restrict__ xb,
    u16* __restrict__ wqT, u16* __restrict__ woT) {
  const int bid = blockIdx.x, tid = threadIdx.x;
  if (bid < 4096) {
    int i = (bid * 256 + tid) * 4;
    float4 v = *(const float4*)&x[i];
    ushort4 p;
    p.x = f2bf(v.x); p.y = f2bf(v.y); p.z = f2bf(v.z); p.w = f2bf(v.w);
    *(ushort4*)&xb[i] = p;
    return;
  }
  __shared__ float tile[32][33];
  int t = bid - 4096;
  const float* in;
  u16* outp;
  int C, bx, by;
  if (t < 3072) { in = w_qkv; outp = wqT; C = 3072; bx = (t % 96) * 32; by = (t / 96) * 32; }
  else { t -= 3072; in = w_out; outp = woT; C = 1024; bx = (t % 32) * 32; by = (t / 32) * 32; }
  const int tx = tid & 31, ty = tid >> 5;
#pragma unroll
  for (int r2 = 0; r2 < 4; ++r2)
    tile[ty + r2 * 8][tx] = in[(size_t)(by + ty + r2 * 8) * C + bx + tx];
  __syncthreads();
#pragma unroll
  for (int r2 = 0; r2 < 4; ++r2)
    outp[(size_t)(bx + ty + r2 * 8) * 1024 + by + tx] = f2bf(tile[tx][ty + r2 * 8]);
}

// ---------------- GEMM 128x128 (R10, best measured): QKV scatter -----------
__global__ __launch_bounds__(256, 3) void gemm_qkv(
    const u16* __restrict__ A, const u16* __restrict__ Bt,
    const float* __restrict__ bias,
    u16* __restrict__ qb, u16* __restrict__ kb, u16* __restrict__ vb,
    int M, int N, int K) {
  __shared__ u16 As[128 * 32];
  __shared__ u16 Bs[128 * 32];
  const int tid = threadIdx.x;
  const int m0 = blockIdx.x * 128;
  const int n0 = blockIdx.y * 128;
  const int lane = tid & 63, w = tid >> 6;
  const int quad = lane >> 4, l16 = lane & 15;
  const int wr = w >> 1, wc = w & 1;

  f32x4 acc[4][4] = {};

  const int r0 = tid >> 2, p0 = tid & 3;
  const int r1 = r0 + 64;
  const int c8 = p0 ^ ((r0 >> 1) & 3);
  const u16* ga0 = A + (size_t)(m0 + r0) * K + c8 * 8;
  const u16* ga1 = A + (size_t)(m0 + r1) * K + c8 * 8;
  const u16* gb0 = Bt + (size_t)(n0 + r0) * K + c8 * 8;
  const u16* gb1 = Bt + (size_t)(n0 + r1) * K + c8 * 8;
  u16* la0 = &As[tid * 8];
  u16* la1 = &As[(tid + 256) * 8];
  u16* lb0 = &Bs[tid * 8];
  u16* lb1 = &Bs[(tid + 256) * 8];

  int aoff[4], boff[4];
#pragma unroll
  for (int i = 0; i < 4; ++i) {
    int ra = wr * 64 + i * 16 + l16;
    aoff[i] = (ra * 4 + (quad ^ ((ra >> 1) & 3))) * 8;
    int rb = wc * 64 + i * 16 + l16;
    boff[i] = (rb * 4 + (quad ^ ((rb >> 1) & 3))) * 8;
  }

  const int nIter = K >> 5;
  for (int kt = 0; kt < nIter; ++kt) {
    __syncthreads();
    const int kk = kt << 5;
    GLOAD_LDS16(ga0 + kk, la0);
    GLOAD_LDS16(ga1 + kk, la1);
    GLOAD_LDS16(gb0 + kk, lb0);
    GLOAD_LDS16(gb1 + kk, lb1);
    __syncthreads();
    bf16x8 af[4], bfr[4];
#pragma unroll
    for (int i = 0; i < 4; ++i) af[i] = *(const bf16x8*)&As[aoff[i]];
#pragma unroll
    for (int j = 0; j < 4; ++j) bfr[j] = *(const bf16x8*)&Bs[boff[j]];
#pragma unroll
    for (int i = 0; i < 4; ++i)
#pragma unroll
      for (int j = 0; j < 4; ++j)
        acc[i][j] = MFMA16(af[i], bfr[j], acc[i][j]);
  }

  const int S = 2048, NH = 16;
#pragma unroll
  for (int i = 0; i < 4; ++i) {
    const int mb = m0 + wr * 64 + i * 16 + quad * 4;
#pragma unroll
    for (int j = 0; j < 4; ++j) {
      const int n = n0 + wc * 64 + j * 16 + l16;
      const float bv = bias[n];
      const int which = n >> 10;      // 0:Q 1:K 2:V (uniform per block)
      const int hn = n & 1023;
      const int h = hn >> 6, d = hn & 63;
      const int b = mb >> 11, s = mb & 2047;
      const int bh = b * NH + h;
      if (which == 2) {
        ushort4 pk;
        pk.x = f2bf(acc[i][j][0] + bv);
        pk.y = f2bf(acc[i][j][1] + bv);
        pk.z = f2bf(acc[i][j][2] + bv);
        pk.w = f2bf(acc[i][j][3] + bv);
        *(ushort4*)&vb[((size_t)bh * 64 + d) * S + s] = pk;  // V transposed
      } else {
        // Q pre-scaled by HD^-0.5 * log2(e): scores land in exp2 domain
        const float sc = (which == 0) ? 0.18033688f : 1.0f;
        u16* dst = (which == 0) ? qb : kb;
#pragma unroll
        for (int r = 0; r < 4; ++r)
          dst[((size_t)bh * S + s + r) * 64 + d] = f2bf((acc[i][j][r] + bv) * sc);
      }
    }
  }
}

// ---------------- GEMM 64x128: out = A @ Bt^T + bias (fp32 out) ----------
__global__ __launch_bounds__(256, 2) void gemm_out(
    const u16* __restrict__ A, const u16* __restrict__ Bt,
    const float* __restrict__ bias, float* __restrict__ outf,
    int M, int N, int K) {
  __shared__ u16 As[64 * 32];
  __shared__ u16 Bs[128 * 32];
  const int tid = threadIdx.x;
  const int m0 = blockIdx.x * 64;
  const int n0 = blockIdx.y * 128;
  const int lane = tid & 63, w = tid >> 6;
  const int quad = lane >> 4, l16 = lane & 15;
  const int wr = w >> 1, wc = w & 1;

  f32x4 acc[2][4] = {};

  const int r0 = tid >> 2, p0 = tid & 3;
  const int c8 = p0 ^ ((r0 >> 1) & 3);
  const u16* ga0 = A + (size_t)(m0 + r0) * K + c8 * 8;
  const u16* gb0 = Bt + (size_t)(n0 + r0) * K + c8 * 8;
  const u16* gb1 = Bt + (size_t)(n0 + r0 + 64) * K + c8 * 8;
  u16* la0 = &As[tid * 8];
  u16* lb0 = &Bs[tid * 8];
  u16* lb1 = &Bs[(tid + 256) * 8];

  int aoff[2], boff[4];
#pragma unroll
  for (int i = 0; i < 2; ++i) {
    int ra = wr * 32 + i * 16 + l16;
    aoff[i] = (ra * 4 + (quad ^ ((ra >> 1) & 3))) * 8;
  }
#pragma unroll
  for (int j = 0; j < 4; ++j) {
    int rb = wc * 64 + j * 16 + l16;
    boff[j] = (rb * 4 + (quad ^ ((rb >> 1) & 3))) * 8;
  }

  const int nIter = K >> 5;
  for (int kt = 0; kt < nIter; ++kt) {
    __syncthreads();
    const int kk = kt << 5;
    GLOAD_LDS16(ga0 + kk, la0);
    GLOAD_LDS16(gb0 + kk, lb0);
    GLOAD_LDS16(gb1 + kk, lb1);
    __syncthreads();
    bf16x8 af[2], bfr[4];
#pragma unroll
    for (int i = 0; i < 2; ++i) af[i] = *(const bf16x8*)&As[aoff[i]];
#pragma unroll
    for (int j = 0; j < 4; ++j) bfr[j] = *(const bf16x8*)&Bs[boff[j]];
#pragma unroll
    for (int i = 0; i < 2; ++i)
#pragma unroll
      for (int j = 0; j < 4; ++j)
        acc[i][j] = MFMA16(af[i], bfr[j], acc[i][j]);
  }

#pragma unroll
  for (int i = 0; i < 2; ++i) {
    const int mb = m0 + wr * 32 + i * 16 + quad * 4;
#pragma unroll
    for (int j = 0; j < 4; ++j) {
      const int n = n0 + wc * 64 + j * 16 + l16;
      const float bv = bias[n];
#pragma unroll
      for (int r = 0; r < 4; ++r)
        outf[(size_t)(mb + r) * N + n] = acc[i][j][r] + bv;
    }
  }
}

// ---------------- flash attention v14: one-tile-deep PV pipeline -----------
// v13 post-mortem: conflicts 0, MfmaUtil still 33% -> per-tile DEPENDENT
// chain QK -> exp2(~512cyc trans) -> ptrans -> PV leaves the matrix pipe idle
// during exp2 (only 2 waves/SIMD, grid-capped). v14 (T15 mechanism): defer
// PV by one tile. In tile kt: QK(kt) then PV(kt-1) -- independent of s(kt),
// so PV's 40 MFMAs execute under exp2(kt)'s trans chain.
//  - P frags (8 x bf16x8) carried in regs, static A/B ping-pong (rule #20
//    safe: explicit pair-unrolled bodies, literal indices only).
//  - V(kt-1) frags read LATE from the LDS buffer that still holds them
//    (buf CUR^1); a second barrier publishes those reads before the
//    overwriting STAGE(kt+1) is issued -- no cross-wave timing races.
//  - Accumulation order across tiles unchanged -> bit-identical output.
__global__ __launch_bounds__(256, 2) void attn_fa(
    const u16* __restrict__ qg, const u16* __restrict__ kg,
    const u16* __restrict__ vg, u16* __restrict__ o) {
  const int S = 2048;
  const int lin = blockIdx.x;
  const int xcd = lin & 7, chunk = lin >> 3;
  const int bh = xcd * 4 + (chunk & 3);
  const int qblk = chunk >> 2;
  const int b = bh >> 4, h = bh & 15;
  const int tid = threadIdx.x, w = tid >> 6, lane = tid & 63;
  const int quad = lane >> 4, l16 = lane & 15;

  __shared__ u16 Ks[2][8192];   // [128 key-rows][8 granules], ^(row&7) swizzle
  __shared__ u16 Vs[2][8192];   // [2 hh][64 d-rows][8 granules], ^(row&7)

  const int q0 = qblk * 128 + w * 32;
  const u16* qp = qg + ((size_t)bh * S + q0 + l16) * 64 + quad * 8;
  const bf16x8 qf00 = *(const bf16x8*)qp;
  const bf16x8 qf01 = *(const bf16x8*)(qp + 32);
  const bf16x8 qf10 = *(const bf16x8*)(qp + 1024);
  const bf16x8 qf11 = *(const bf16x8*)(qp + 1024 + 32);

  f32x4 accO0[4] = {}, accO1[4] = {};
  f32x4 accL0 = {}, accL1 = {};

  bf16x8 ones;
#pragma unroll
  for (int i = 0; i < 8; ++i) ones[i] = (__bf16)1.0f;

  const u16* kbase = kg + (size_t)bh * S * 64;
  const u16* vbase = vg + (size_t)bh * 64 * S;

  const int sr0 = tid >> 3, sp0 = tid & 7;
  const int c8s = sp0 ^ (sr0 & 7);
  const u16* kSrc = kbase + (size_t)sr0 * 64 + c8s * 8;
  const u16* vSrc = vbase + (size_t)sr0 * S + c8s * 8;

  const int kgA = (quad ^ (l16 & 7)) * 8;
  const int kgB = ((quad + 4) ^ (l16 & 7)) * 8;

  bf16x8 pfA[8], pfB[8];          // carried P fragments (ping-pong)

#define STAGE_KV(KT, NB)                                                      \
  {                                                                           \
    _Pragma("unroll")                                                         \
    for (int seg = 0; seg < 4; ++seg) {                                       \
      GLOAD_LDS16(kSrc + (size_t)((KT) * 128 + seg * 32) * 64,                \
                  &Ks[NB][(seg * 256 + tid) * 8]);                            \
      GLOAD_LDS16(vSrc + (size_t)(seg & 1) * 32 * S + (KT) * 128 +            \
                      (seg >> 1) * 64,                                        \
                  &Vs[NB][(seg * 256 + tid) * 8]);                            \
    }                                                                         \
  }

#define QK_BLOCK(KC)                                                          \
  bf16x8 kf00[4], kf01[4], kf10[4], kf11[4];                                  \
  _Pragma("unroll")                                                           \
  for (int ct = 0; ct < 4; ++ct) {                                            \
    const int rb0 = (ct * 16 + l16) * 64;                                     \
    const int rb1 = (64 + ct * 16 + l16) * 64;                                \
    kf00[ct] = *(const bf16x8*)&(KC)[rb0 + kgA];                              \
    kf01[ct] = *(const bf16x8*)&(KC)[rb0 + kgB];                              \
    kf10[ct] = *(const bf16x8*)&(KC)[rb1 + kgA];                              \
    kf11[ct] = *(const bf16x8*)&(KC)[rb1 + kgB];                              \
  }                                                                           \
  f32x4 s0[4] = {}, s1[4] = {}, t0[4] = {}, t1[4] = {};                       \
  __builtin_amdgcn_s_setprio(1);                                              \
  _Pragma("unroll")                                                           \
  for (int ct = 0; ct < 4; ++ct) {                                            \
    s0[ct] = MFMA16(kf00[ct], qf00, s0[ct]);                                  \
    s0[ct] = MFMA16(kf01[ct], qf01, s0[ct]);                                  \
    s1[ct] = MFMA16(kf00[ct], qf10, s1[ct]);                                  \
    s1[ct] = MFMA16(kf01[ct], qf11, s1[ct]);                                  \
    t0[ct] = MFMA16(kf10[ct], qf00, t0[ct]);                                  \
    t0[ct] = MFMA16(kf11[ct], qf01, t0[ct]);                                  \
    t1[ct] = MFMA16(kf10[ct], qf10, t1[ct]);                                  \
    t1[ct] = MFMA16(kf11[ct], qf11, t1[ct]);                                  \
  }                                                                           \
  __builtin_amdgcn_s_setprio(0);

#define SM_BLOCK(PFC)                                                         \
  _Pragma("unroll")                                                           \
  for (int ct = 0; ct < 4; ++ct)                                              \
    _Pragma("unroll")                                                         \
    for (int r = 0; r < 4; ++r) {                                             \
      s0[ct][r] = __builtin_amdgcn_exp2f(s0[ct][r]);                          \
      s1[ct][r] = __builtin_amdgcn_exp2f(s1[ct][r]);                          \
      t0[ct][r] = __builtin_amdgcn_exp2f(t0[ct][r]);                          \
      t1[ct][r] = __builtin_amdgcn_exp2f(t1[ct][r]);                          \
    }                                                                         \
  PFC[0] = ptrans(s0[0], s0[1]);                                              \
  PFC[1] = ptrans(s0[2], s0[3]);                                              \
  PFC[2] = ptrans(s1[0], s1[1]);                                              \
  PFC[3] = ptrans(s1[2], s1[3]);                                              \
  PFC[4] = ptrans(t0[0], t0[1]);                                              \
  PFC[5] = ptrans(t0[2], t0[3]);                                              \
  PFC[6] = ptrans(t1[0], t1[1]);                                              \
  PFC[7] = ptrans(t1[2], t1[3]);

#define PV_BLOCK(PFP)                                                         \
  __builtin_amdgcn_s_setprio(1);                                              \
  accL0 = MFMA16(ones, PFP[0], accL0);                                        \
  accL0 = MFMA16(ones, PFP[1], accL0);                                        \
  accL1 = MFMA16(ones, PFP[2], accL1);                                        \
  accL1 = MFMA16(ones, PFP[3], accL1);                                        \
  accL0 = MFMA16(ones, PFP[4], accL0);                                        \
  accL0 = MFMA16(ones, PFP[5], accL0);                                        \
  accL1 = MFMA16(ones, PFP[6], accL1);                                        \
  accL1 = MFMA16(ones, PFP[7], accL1);                                        \
  _Pragma("unroll")                                                           \
  for (int ct = 0; ct < 4; ++ct) {                                            \
    accO0[ct] = MFMA16(vp0[ct], PFP[0], accO0[ct]);                           \
    accO0[ct] = MFMA16(vp1[ct], PFP[1], accO0[ct]);                           \
    accO1[ct] = MFMA16(vp0[ct], PFP[2], accO1[ct]);                           \
    accO1[ct] = MFMA16(vp1[ct], PFP[3], accO1[ct]);                           \
    accO0[ct] = MFMA16(vp2[ct], PFP[4], accO0[ct]);                           \
    accO0[ct] = MFMA16(vp3[ct], PFP[5], accO0[ct]);                           \
    accO1[ct] = MFMA16(vp2[ct], PFP[6], accO1[ct]);                           \
    accO1[ct] = MFMA16(vp3[ct], PFP[7], accO1[ct]);                           \
  }                                                                           \
  __builtin_amdgcn_s_setprio(0);

#define VREAD(VP)                                                             \
  bf16x8 vp0[4], vp1[4], vp2[4], vp3[4];                                      \
  _Pragma("unroll")                                                           \
  for (int ct = 0; ct < 4; ++ct) {                                            \
    const int rb0 = (ct * 16 + l16) * 64;                                     \
    vp0[ct] = *(const bf16x8*)&(VP)[rb0 + kgA];                               \
    vp1[ct] = *(const bf16x8*)&(VP)[rb0 + kgB];                               \
    vp2[ct] = *(const bf16x8*)&(VP)[4096 + rb0 + kgA];                        \
    vp3[ct] = *(const bf16x8*)&(VP)[4096 + rb0 + kgB];                        \
  }

  // BODY(kt): barrier1 (glds(kt) landed) -> read K(kt) + V(kt-1) ->
  // barrier2 (reads published) -> STAGE(kt+1) over buf CUR^1 ->
  // QK(kt) -> PV(kt-1) [independent, fills matrix pipe under exp2] ->
  // exp2+ptrans(kt).
#define ATTN_BODY(KT, CUR, PFP, PFC, PRE)                                     \
  {                                                                           \
    __syncthreads();                                                          \
    const u16* Kc = Ks[CUR];                                                  \
    const u16* Vp = Vs[(CUR) ^ 1];                                            \
    VREAD(Vp)                                                                 \
    QK_BLOCK(Kc)                                                              \
    __syncthreads();                                                          \
    if (PRE) STAGE_KV((KT) + 1, (CUR) ^ 1);                                   \
    PV_BLOCK(PFP)                                                             \
    SM_BLOCK(PFC)                                                             \
  }

  // ---- prologue: tile 0 (QK+SM only, no PV yet) ----
  STAGE_KV(0, 0);
  __syncthreads();            // glds(0) landed
  STAGE_KV(1, 1);             // buf1 virgin: safe to issue immediately
  {
    const u16* Kc = Ks[0];
    QK_BLOCK(Kc)
    SM_BLOCK(pfA)
  }

  // ---- pipelined main loop: bodies 1..14 in static A/B pairs, then 15 ----
  for (int kt = 1; kt < 15; kt += 2) {
    ATTN_BODY(kt, 1, pfA, pfB, true);
    ATTN_BODY(kt + 1, 0, pfB, pfA, true);
  }
  ATTN_BODY(15, 1, pfA, pfB, false);

  // ---- epilogue: PV for tile 15 (V(15) still intact in Vs[1]) ----
  {
    const u16* Vp = Vs[1];
    VREAD(Vp)
    PV_BLOCK(pfB)
  }

  const float inv0 = 1.f / accL0[0], inv1 = 1.f / accL1[0];

  const int s0r = q0 + l16, s1r = q0 + 16 + l16;
#pragma unroll
  for (int ct = 0; ct < 4; ++ct) {
    ushort4 pk;
    pk.x = f2bf(accO0[ct][0] * inv0);
    pk.y = f2bf(accO0[ct][1] * inv0);
    pk.z = f2bf(accO0[ct][2] * inv0);
    pk.w = f2bf(accO0[ct][3] * inv0);
    *(ushort4*)&o[(size_t)(b * S + s0r) * 1024 + h * 64 + ct * 16 + quad * 4] = pk;
    pk.x = f2bf(accO1[ct][0] * inv1);
    pk.y = f2bf(accO1[ct][1] * inv1);
    pk.z = f2bf(accO1[ct][2] * inv1);
    pk.w = f2bf(accO1[ct][3] * inv1);
    *(ushort4*)&o[(size_t)(b * S + s1r) * 1024 + h * 64 + ct * 16 + quad * 4] = pk;
  }
#undef ATTN_BODY
#undef VREAD
#undef PV_BLOCK
#undef SM_BLOCK
#undef QK_BLOCK
#undef STAGE_KV
}

// ---------------- launch ----------------

extern "C" void kernel_launch(void* const* d_in, const int* in_sizes, int n_in,
                              void* d_out, int out_size, void* d_ws, size_t ws_size,
                              hipStream_t stream) {
  const float* x = (const float*)d_in[0];
  const float* w_qkv = (const float*)d_in[1];
  const float* b_qkv = (const float*)d_in[2];
  const float* w_out = (const float*)d_in[3];
  const float* b_out = (const float*)d_in[4];
  float* out = (float*)d_out;

  u16* xb = (u16*)d_ws;                 // [4096,1024]
  u16* wqT = xb + 4096 * 1024;          // [3072,1024]
  u16* woT = wqT + 3072 * 1024;         // [1024,1024]
  u16* qb = woT + 1024 * 1024;          // [32,2048,64] (pre-scaled)
  u16* kb = qb + 4194304;               // [32,2048,64]
  u16* vb = kb + 4194304;               // [32,64,2048]
  u16* ao = vb + 4194304;               // [4096,1024]

  prep<<<8192, 256, 0, stream>>>(x, w_qkv, w_out, xb, wqT, woT);
  gemm_qkv<<<dim3(32, 24), 256, 0, stream>>>(xb, wqT, b_qkv, qb, kb, vb,
                                             4096, 3072, 1024);
  attn_fa<<<512, 256, 0, stream>>>(qb, kb, vb, ao);
  gemm_out<<<dim3(64, 8), 256, 0, stream>>>(ao, woT, b_out, out,
                                            4096, 1024, 1024);
}